// Round 2
// baseline (278.023 us; speedup 1.0000x reference)
//
#include <hip/hip_runtime.h>
#include <float.h>

typedef unsigned short u16;
typedef unsigned int u32;
typedef unsigned char u8;

typedef float f32x4 __attribute__((ext_vector_type(4)));
typedef short bh8   __attribute__((ext_vector_type(8)));   // 8 bf16 carried as shorts

// B=2, N=8192, M=4096, C=64, K=16, HID=256
__device__ __forceinline__ float bf(u16 u) { return __uint_as_float(((u32)u) << 16); }
__device__ __forceinline__ u16 f2bf(float v) {
    u32 x = __float_as_uint(v);
    u32 r = x + 0x7fffu + ((x >> 16) & 1u);
    return (u16)(r >> 16);
}
// Dtype probe on EVEN u16 positions of a large ~N(0,1) buffer (pcl_noise).
__device__ __forceinline__ int detect_f32(const void* probe) {
    const u16* u = (const u16*)probe;
    u16 v = u[(threadIdx.x & 63) * 2];
    int e = (int)((v >> 7) & 0xFF);
    int moderate = (e >= 100) && (e <= 140);
    return __popcll(__ballot(moderate)) < 48;   // few moderate -> fp32
}
__device__ __forceinline__ float ldv(int f32, const void* p, int i) {
    return f32 ? ((const float*)p)[i] : bf(((const u16*)p)[i]);
}
// fma-chain dot (matches the validated selection math from the passing rounds).
__device__ __forceinline__ float dot3(float x0, float x1, float x2,
                                      float y0, float y1, float y2) {
    return __fmaf_rn(x2, y2, __fmaf_rn(x1, y1, __fmul_rn(x0, y0)));
}
// Monotonic u32 key: ordering on keys == ordering on float distances.
__device__ __forceinline__ u32 mkey32(float d) {
    u32 f = __float_as_uint(d);
    return f ^ (u32)((((int)f) >> 31) | 0x80000000);
}
// 16B LDS/global load as a bf16x8 fragment (bit-pattern carrier).
__device__ __forceinline__ bh8 ldb(const void* p) { return *(const bh8*)p; }
// Guide-verified intrinsic path: A row = lane&15, B col = lane&15,
// D: row = 4*(lane>>4)+reg, col = lane&15 (HW-verified m89 mapping).
// A/B k-slot conventions are identical on both operands, so any HW k-permutation cancels.
__device__ __forceinline__ f32x4 mfma16(bh8 a, bh8 b, f32x4 c) {
    return __builtin_amdgcn_mfma_f32_16x16x32_bf16(a, b, c, 0, 0, 0);
}

// ---- canon: w2b | w1a | w1b packed as BF16 PAIRS (halves the weight stream) ----
__global__ __launch_bounds__(256) void k_canon(const void* __restrict__ probe,
                                               const void* __restrict__ w2b,
                                               const void* __restrict__ w1a,
                                               const void* __restrict__ w1b,
                                               u32* __restrict__ canonb) {
    int f32 = detect_f32(probe);
    int ix = blockIdx.x * 256 + threadIdx.x;       // 0..16383 (pairs)
    const void* src; int j;
    if (ix < 8192)       { src = w2b; j = ix; }          // 64x256 -> 8192 pairs
    else if (ix < 14336) { src = w1a; j = ix - 8192; }   // 64x192 -> 6144 pairs
    else                 { src = w1b; j = ix - 14336; }  // 64x64  -> 2048 pairs
    u32 out;
    if (f32) {
        const float* f = (const float*)src;
        out = ((u32)f2bf(f[2*j+1]) << 16) | (u32)f2bf(f[2*j]);
    } else {
        const u16* su = (const u16*)src;
        out = ((u32)su[2*j+1] << 16) | (u32)su[2*j];
    }
    canonb[ix] = out;
}

// ---- prep: pcl -> float4 (x,y,z,sumsq) ----
__global__ __launch_bounds__(256) void k_prep(const void* __restrict__ probe,
                                              const void* __restrict__ pcl,
                                              float4* __restrict__ pcl4) {
    int f32 = detect_f32(probe);
    int i = blockIdx.x * 256 + threadIdx.x;        // 0..8191
    float x = ldv(f32, pcl, i*3+0), y = ldv(f32, pcl, i*3+1), z = ldv(f32, pcl, i*3+2);
    float s = __fadd_rn(__fadd_rn(__fmul_rn(x,x), __fmul_rn(y,y)), __fmul_rn(z,z));
    pcl4[i] = make_float4(x, y, z, s);
}

// ---- argmin over M for each noise point; 16 lanes per query; 32 KB chunked tile ----
__global__ __launch_bounds__(256) void k_close(const float4* __restrict__ pcl4,
                                               const void* __restrict__ noise,
                                               u16* __restrict__ cidx) {
    __shared__ __align__(16) float4 tile[2048];
    int f32 = detect_f32(noise);
    int t = threadIdx.x, g = t >> 4, s = t & 15;
    int q = blockIdx.x * 16 + g;                   // global noise-point id
    int b = q >> 13;
    const float4* src = pcl4 + ((size_t)b << 12);
    float x0 = ldv(f32, noise, q*3+0), x1 = ldv(f32, noise, q*3+1), x2 = ldv(f32, noise, q*3+2);
    float sx = __fadd_rn(__fadd_rn(__fmul_rn(x0,x0), __fmul_rn(x1,x1)), __fmul_rn(x2,x2));
    float bd = FLT_MAX; int bi = 0;
    for (int ch = 0; ch < 2; ++ch) {
        __syncthreads();
#pragma unroll
        for (int i = 0; i < 8; ++i) { int ix = t + (i << 8); tile[ix] = src[(ch << 11) + ix]; }
        __syncthreads();
        for (int j = 0; j < 128; ++j) {
            int cl = (j << 4) + s;                 // lane-interleaved: conflict-free LDS
            float4 p = tile[cl];
            float dot = dot3(x0, x1, x2, p.x, p.y, p.z);
            float d = __fadd_rn(__fsub_rn(sx, __fmul_rn(2.0f, dot)), p.w);
            int c = (ch << 11) + cl;               // strictly increasing within thread
            if (d < bd) { bd = d; bi = c; }        // -> first-min on ties
        }
    }
#pragma unroll
    for (int m = 8; m >= 1; m >>= 1) {             // lexicographic (d, idx) merge
        float od = __shfl_xor(bd, m);
        int   oi = __shfl_xor(bi, m);
        if (od < bd || (od == bd && oi < bi)) { bd = od; bi = oi; }
    }
    if (s == 0) cidx[q] = (u16)(bi & 4095);        // masked
}

// ---- k_knnh v4: histogram radix-select, ONE BLOCK (4 waves) per query ----
__global__ __launch_bounds__(256) void k_knnh(const float4* __restrict__ pcl4,
                                              u16* __restrict__ knn) {
    __shared__ u8  bins[4096];                     // 4 KB: per-candidate bin cache
    __shared__ u32 hist[256];                      // 1 KB
    __shared__ u32 skey[256];                      // 1 KB survivors
    __shared__ u16 sidx[256];                      // 0.5 KB
    __shared__ float rmn[4], rmx[4];
    __shared__ u32 scnt;
    __shared__ int ibst;
    int t = threadIdx.x, lane = t & 63, wv = t >> 6;
    int q = blockIdx.x;                            // 0..8191
    int b = q >> 12;
    const float4* src = pcl4 + ((size_t)b << 12);
    float4 Q = src[q & 4095];
    float x0 = Q.x, x1 = Q.y, x2 = Q.z, sx = Q.w;
    if (t < 256) hist[t] = 0;                      // zero hist
    if (t == 0) scnt = 0;
    // sample pass: 256 candidates (stride 16) -> block min/max scale estimate
    {
        float4 p = src[t << 4];
        float dot = dot3(x0, x1, x2, p.x, p.y, p.z);
        float d = __fadd_rn(__fsub_rn(sx, __fmul_rn(2.0f, dot)), p.w);
        float mn = d, mx = d;
#pragma unroll
        for (int m = 32; m >= 1; m >>= 1) {
            mn = fminf(mn, __shfl_xor(mn, m));
            mx = fmaxf(mx, __shfl_xor(mx, m));
        }
        if (lane == 0) { rmn[wv] = mn; rmx[wv] = mx; }
    }
    __syncthreads();
    float dmn = fminf(fminf(rmn[0], rmn[1]), fminf(rmn[2], rmn[3]));
    float dmx = fmaxf(fmaxf(rmx[0], rmx[1]), fmaxf(rmx[2], rmx[3]));
    float sc = 1024.0f / fmaxf(dmx - dmn, 1e-20f); // fine bins over lowest quarter
    // hist pass: 16 candidates/thread, bin cached, clamp-bin 255 never counted
#pragma unroll 4
    for (int j = 0; j < 16; ++j) {
        int cin = (j << 8) + t;
        float4 p = src[cin];
        float dot = dot3(x0, x1, x2, p.x, p.y, p.z);
        float d = __fadd_rn(__fsub_rn(sx, __fmul_rn(2.0f, dot)), p.w);
        float fb = fminf(fmaxf((d - dmn) * sc, 0.0f), 255.0f);
        int bn = (int)fb;
        bins[cin] = (u8)bn;
        if (bn < 255) atomicAdd(&hist[bn], 1u);    // no hot-spot
    }
    __syncthreads();
    // prefix over bins 0..254 by wave 0 -> first bin with cum >= 16
    if (t < 64) {
        u32 c0 = hist[4*lane], c1 = hist[4*lane+1];
        u32 c2 = hist[4*lane+2], c3 = hist[4*lane+3];
        u32 loc = c0 + c1 + c2 + c3;
        u32 x = loc;
#pragma unroll
        for (int off = 1; off < 64; off <<= 1) { u32 v = __shfl_up(x, off); if (lane >= off) x += v; }
        u32 excl = x - loc;
        int cand = 999;                            // 999 -> everything survives -> fallback
        if (excl + c0 >= 16u) cand = 4*lane;
        else if (excl + c0 + c1 >= 16u) cand = 4*lane + 1;
        else if (excl + c0 + c1 + c2 >= 16u) cand = 4*lane + 2;
        else if (excl + loc >= 16u) cand = 4*lane + 3;
#pragma unroll
        for (int m = 32; m >= 1; m >>= 1) cand = min(cand, __shfl_xor(cand, m));
        if (lane == 0) ibst = cand;
    }
    __syncthreads();
    int bstar = ibst;
    // gather pass: survivors from the LDS bin cache; reload exact d only for them
#pragma unroll
    for (int j = 0; j < 16; ++j) {
        int cin = (j << 8) + t;
        if ((int)bins[cin] <= bstar) {
            u32 pos = atomicAdd(&scnt, 1u);
            if (pos < 256u) {
                float4 p = src[cin];
                float dot = dot3(x0, x1, x2, p.x, p.y, p.z);
                float d = __fadd_rn(__fsub_rn(sx, __fmul_rn(2.0f, dot)), p.w);
                skey[pos] = mkey32(d);
                sidx[pos] = (u16)cin;
            }
        }
    }
    __syncthreads();
    u32 n = scnt;
    if (n <= 256u) {
        // rank-select: rank = #survivors lex-(key,idx)-smaller; rank<16 -> output
        for (u32 e = (u32)t; e < n; e += 256u) {
            u32 k = skey[e]; u32 i = (u32)sidx[e];
            int rank = 0;
            for (u32 j = 0; j < n; ++j) {
                u32 kj = skey[j]; u32 ij = (u32)sidx[j];
                rank += (kj < k) || (kj == k && ij < i);
            }
            if (rank < 16) knn[((size_t)q << 4) + rank] = (u16)i;
        }
    } else if (t < 64) {
        // exact brute-force fallback on wave 0 (validated ripple + tournament)
        u32 k0=~0u,k1=~0u,k2=~0u,k3=~0u,k4=~0u,k5=~0u,k6=~0u,k7=~0u,
            k8=~0u,k9=~0u,k10=~0u,k11=~0u,k12=~0u,k13=~0u,k14=~0u,k15=~0u;
        u32 i0r=0,i1r=0,i2r=0,i3r=0,i4r=0,i5r=0,i6r=0,i7r=0,
            i8r=0,i9r=0,i10r=0,i11r=0,i12r=0,i13r=0,i14r=0,i15r=0;
        for (int j = 0; j < 64; ++j) {
            int cin = (j << 6) + lane;             // ascending per lane -> stable ties
            float4 p = src[cin];
            float dot = dot3(x0, x1, x2, p.x, p.y, p.z);
            float d = __fadd_rn(__fsub_rn(sx, __fmul_rn(2.0f, dot)), p.w);
            u32 v = mkey32(d); u32 vi = (u32)cin;
            if (v < k15) {
                { u32 c_=(v<k0); u32 nk=c_?v:k0; u32 nv=c_?k0:v; u32 ni=c_?vi:i0r; u32 nj=c_?i0r:vi; k0=nk;i0r=ni;v=nv;vi=nj; }
                { u32 c_=(v<k1); u32 nk=c_?v:k1; u32 nv=c_?k1:v; u32 ni=c_?vi:i1r; u32 nj=c_?i1r:vi; k1=nk;i1r=ni;v=nv;vi=nj; }
                { u32 c_=(v<k2); u32 nk=c_?v:k2; u32 nv=c_?k2:v; u32 ni=c_?vi:i2r; u32 nj=c_?i2r:vi; k2=nk;i2r=ni;v=nv;vi=nj; }
                { u32 c_=(v<k3); u32 nk=c_?v:k3; u32 nv=c_?k3:v; u32 ni=c_?vi:i3r; u32 nj=c_?i3r:vi; k3=nk;i3r=ni;v=nv;vi=nj; }
                { u32 c_=(v<k4); u32 nk=c_?v:k4; u32 nv=c_?k4:v; u32 ni=c_?vi:i4r; u32 nj=c_?i4r:vi; k4=nk;i4r=ni;v=nv;vi=nj; }
                { u32 c_=(v<k5); u32 nk=c_?v:k5; u32 nv=c_?k5:v; u32 ni=c_?vi:i5r; u32 nj=c_?i5r:vi; k5=nk;i5r=ni;v=nv;vi=nj; }
                { u32 c_=(v<k6); u32 nk=c_?v:k6; u32 nv=c_?k6:v; u32 ni=c_?vi:i6r; u32 nj=c_?i6r:vi; k6=nk;i6r=ni;v=nv;vi=nj; }
                { u32 c_=(v<k7); u32 nk=c_?v:k7; u32 nv=c_?k7:v; u32 ni=c_?vi:i7r; u32 nj=c_?i7r:vi; k7=nk;i7r=ni;v=nv;vi=nj; }
                { u32 c_=(v<k8); u32 nk=c_?v:k8; u32 nv=c_?k8:v; u32 ni=c_?vi:i8r; u32 nj=c_?i8r:vi; k8=nk;i8r=ni;v=nv;vi=nj; }
                { u32 c_=(v<k9); u32 nk=c_?v:k9; u32 nv=c_?k9:v; u32 ni=c_?vi:i9r; u32 nj=c_?i9r:vi; k9=nk;i9r=ni;v=nv;vi=nj; }
                { u32 c_=(v<k10); u32 nk=c_?v:k10; u32 nv=c_?k10:v; u32 ni=c_?vi:i10r; u32 nj=c_?i10r:vi; k10=nk;i10r=ni;v=nv;vi=nj; }
                { u32 c_=(v<k11); u32 nk=c_?v:k11; u32 nv=c_?k11:v; u32 ni=c_?vi:i11r; u32 nj=c_?i11r:vi; k11=nk;i11r=ni;v=nv;vi=nj; }
                { u32 c_=(v<k12); u32 nk=c_?v:k12; u32 nv=c_?k12:v; u32 ni=c_?vi:i12r; u32 nj=c_?i12r:vi; k12=nk;i12r=ni;v=nv;vi=nj; }
                { u32 c_=(v<k13); u32 nk=c_?v:k13; u32 nv=c_?k13:v; u32 ni=c_?vi:i13r; u32 nj=c_?i13r:vi; k13=nk;i13r=ni;v=nv;vi=nj; }
                { u32 c_=(v<k14); u32 nk=c_?v:k14; u32 nv=c_?k14:v; u32 ni=c_?vi:i14r; u32 nj=c_?i14r:vi; k14=nk;i14r=ni;v=nv;vi=nj; }
                { u32 c_=(v<k15); u32 nk=c_?v:k15; u32 nv=c_?k15:v; u32 ni=c_?vi:i15r; u32 nj=c_?i15r:vi; k15=nk;i15r=ni;v=nv;vi=nj; }
            }
        }
        u32 myres = 0;
        for (int o = 0; o < 16; ++o) {
            u32 bk = k0, bi2 = i0r;
#pragma unroll
            for (int m = 32; m >= 1; m >>= 1) {
                u32 ok = __shfl_xor(bk, m), oi = __shfl_xor(bi2, m);
                if (ok < bk || (ok == bk && oi < bi2)) { bk = ok; bi2 = oi; }
            }
            if (lane == o) myres = bi2;
            if (k0 == bk && i0r == bi2) {          // winner lane pops its head
                k0=k1; i0r=i1r; k1=k2; i1r=i2r; k2=k3; i2r=i3r; k3=k4; i3r=i4r;
                k4=k5; i4r=i5r; k5=k6; i5r=i6r; k6=k7; i6r=i7r; k7=k8; i7r=i8r;
                k8=k9; i8r=i9r; k9=k10; i9r=i10r; k10=k11; i10r=i11r; k11=k12; i11r=i12r;
                k12=k13; i12r=i13r; k13=k14; i13r=i14r; k14=k15; i14r=i15r;
                k15=~0u; i15r=0xFFFFu;
            }
        }
        if (lane < 16) knn[((size_t)q << 4) + lane] = (u16)myres;
    }
}

// ---- fused tail v5b: all four MLP layers on MFMA (16x16x32 bf16 builtin), 16 q/block.
// Activations carried as bf16 hi+lo residual pairs (fp32-equivalent precision);
// weights = the already-validated bf16 canonb stream.  LDS arena 38.8 KB -> 4 blk/CU.
//
// LDS arena layout (bytes):
//   [0,     4352)  dpb_hi : 16 q x 17 slots x 16B  (delta|cp bf16-hi, slot=k, +1 pad slot/row)
//                   ... overlaid later by h1 (16 q x 272B) after dpb is dead
//   [4352,  8704)  dpb_lo : same, bf16-lo residuals
//   [8704,  9984)  wbt    : 16 k x 20 f32 (softmax weights, transposed, padded row)
//   [9984, 10048)  wsb    : 16 f32 (sum-of-weights / den)
//   [10048,10560)  jbuf   : 16 q x 16 u16 neighbor ids
//   [10560,27200)  hb     : 16 q x 1040B (256 bf16 hi | 256 bf16 lo | 16B pad)
//   [27200,39744)  df     : 16 q x 784B  (192 bf16 hi [cf|co|pf] | 192 lo | 16B pad)
__global__ __launch_bounds__(256, 4) void k_tail(const float4* __restrict__ pcl4,
                                                 const void* __restrict__ noise,
                                                 const void* __restrict__ feat,
                                                 const u16* __restrict__ cidx,
                                                 const u16* __restrict__ knn,
                                                 const void* __restrict__ w2a,
                                                 const void* __restrict__ b2a,
                                                 const void* __restrict__ g2a,
                                                 const void* __restrict__ bt2a,
                                                 const u32* __restrict__ canonb,
                                                 const void* __restrict__ b2b,
                                                 const void* __restrict__ b1a,
                                                 const void* __restrict__ g1a,
                                                 const void* __restrict__ bt1a,
                                                 const void* __restrict__ b1b,
                                                 void* __restrict__ outp) {
    __shared__ __align__(16) char arena[39744];
    char* dpb_hi = arena;                 // 4352
    char* dpb_lo = arena + 4352;          // 4352
    char* wbt    = arena + 8704;          // 1280
    char* wsbp   = arena + 9984;          // 64
    u16*  jbuf   = (u16*)(arena + 10048); // 512
    char* hbm_   = arena + 10560;         // 16640
    char* dfm    = arena + 27200;         // 12544
    char* h1m    = arena;                 // overlays dpb_hi (dead after hidden phase)

    int f32 = detect_f32(noise);
    int t = threadIdx.x, lane = t & 63, wv = t >> 6;
    int g = lane >> 4, l15 = lane & 15;
    int qbb = blockIdx.x * 16;
    int o_lane = wv * 16 + l15;           // output channel owned in layers 2/1d/2d
    const float rbn = 1.0f / sqrtf(1.0f + 1e-5f);
    const char* cb = (const char*)canonb;
    const f32x4 zero4 = {0.f, 0.f, 0.f, 0.f};

    // ---- per-lane params: hidden B-frags (w2a * bn_scale; groups 0,1 = hi, group 2 = lo),
    //      of2 per hidden channel, layer-1d/2d scalars ----
    float of2r[4];
    bh8 wH[4];
#pragma unroll
    for (int j = 0; j < 4; ++j) {
        int oh = wv*64 + j*16 + l15;
        float sc = ldv(f32, g2a, oh) * rbn;
        of2r[j] = ldv(f32, b2a, oh) * sc + ldv(f32, bt2a, oh);
        bh8 wz = (bh8){0,0,0,0,0,0,0,0};
        if (g < 3) {
#pragma unroll
            for (int c = 0; c < 6; ++c) {
                float wval = ldv(f32, w2a, oh*6 + c) * sc;
                u16 h = f2bf(wval);
                u16 e = (g == 2) ? f2bf(wval - bf(h)) : h;
                wz[c] = (short)e;
            }
        }
        wH[j] = wz;
    }
    float s1o  = ldv(f32, g1a, o_lane) * rbn;
    float o1o  = ldv(f32, b1a, o_lane) * s1o + ldv(f32, bt1a, o_lane);
    float b2bo = ldv(f32, b2b, o_lane);
    float b1fo = ldv(f32, b1b, o_lane);

    // ---- preamble: per (query, neighbor-slot) delta/cp -> dpb hi/lo, softmax weights ----
    {
        int s = lane & 15;                         // neighbor slot
        int ql = wv*4 + (lane >> 4);               // local query 0..15
        int q = qbb + ql;
        int b = q >> 13;
        int pbase = b << 12;
        int ci = ((int)cidx[q]) & 4095;
        float4 cp = pcl4[pbase + ci];
        float x0 = ldv(f32, noise, q*3+0), x1 = ldv(f32, noise, q*3+1), x2 = ldv(f32, noise, q*3+2);
        float e = 0.0f;
        if (s >= 1) {
            int jk = ((int)knn[(size_t)(pbase + ci) * 16 + s]) & 4095;
            float4 p = pcl4[pbase + jk];
            float d0 = p.x - x0, d1 = p.y - x1, d2 = p.z - x2;
            float dst = sqrtf(__fadd_rn(__fadd_rn(__fmul_rn(d0,d0), __fmul_rn(d1,d1)), __fmul_rn(d2,d2)));
            e = expf(-10.0f * dst);
            float v6[6] = {d0, d1, d2, cp.x, cp.y, cp.z};
            bh8 HW = (bh8){0,0,0,0,0,0,0,0};
            bh8 LW = (bh8){0,0,0,0,0,0,0,0};
#pragma unroll
            for (int c = 0; c < 6; ++c) {
                u16 hh = f2bf(v6[c]);
                u16 ll = f2bf(v6[c] - bf(hh));
                HW[c] = (short)hh;
                LW[c] = (short)ll;
            }
            *(bh8*)(dpb_hi + (ql*17 + s)*16) = HW;
            *(bh8*)(dpb_lo + (ql*17 + s)*16) = LW;
            jbuf[ql*16 + s] = (u16)jk;
        }
        float es = e;
#pragma unroll
        for (int m = 8; m >= 1; m >>= 1) es += __shfl_xor(es, m, 16);
        float den = es + 1e-7f;
        if (s >= 1) *(float*)(wbt + s*80 + ql*4) = e / den;
        if (s == 0) *(float*)(wsbp + ql*4) = es / den;
    }
    __syncthreads();

    // ---- cf/co (lane = feature channel): gather-weighted, write straight into df ----
#pragma unroll
    for (int qq = 0; qq < 4; ++qq) {
        int qloc = wv*4 + qq;
        int q = qbb + qloc;
        int b = q >> 13;
        int pbase = b << 12;
        int ci = ((int)cidx[q]) & 4095;
        size_t fcb = ((size_t)(pbase + ci)) << 6;
        float c0, c1 = 0.0f;
        if (f32) {
            const float* ff = (const float*)feat;
            c0 = ff[fcb + lane];
#pragma unroll
            for (int k = 1; k < 16; ++k) {
                float wk = *(const float*)(wbt + k*80 + qloc*4);
                c1 += wk * ff[(((size_t)(pbase + (int)jbuf[qloc*16 + k])) << 6) + lane];
            }
        } else {
            const u16* fb = (const u16*)feat;
            c0 = bf(fb[fcb + lane]);
#pragma unroll
            for (int k = 1; k < 16; ++k) {
                float wk = *(const float*)(wbt + k*80 + qloc*4);
                c1 += wk * bf(fb[(((size_t)(pbase + (int)jbuf[qloc*16 + k])) << 6) + lane]);
            }
        }
        char* dr = dfm + qloc*784;
        u16 h0 = f2bf(c0); u16 l0 = f2bf(c0 - bf(h0));
        u16 h1v = f2bf(c1); u16 l1v = f2bf(c1 - bf(h1v));
        *(u16*)(dr + (size_t)lane*2)         = h0;   // cf hi (cols 0..63)
        *(u16*)(dr + (size_t)(192+lane)*2)   = l0;   // cf lo
        *(u16*)(dr + (size_t)(64+lane)*2)    = h1v;  // co hi (cols 64..127)
        *(u16*)(dr + (size_t)(256+lane)*2)   = l1v;  // co lo
    }

    // ---- hidden layer on MFMA: A rows = queries (l15); k-groups g0=hi(x),g1=lo(x),g2=hi(x),g3=0;
    //      B groups g0,g1 = hi(w*sc), g2 = lo(w*sc), g3 = 0  =>  x*w to ~2^-16 rel.
    //      Per-k BN+ReLU epilogue, wk-weighted sum into hb. ----
    {
        f32x4 hba[4];
#pragma unroll
        for (int j = 0; j < 4; ++j) hba[j] = zero4;
#pragma unroll
        for (int k = 1; k < 16; ++k) {
            bh8 af;
            if (g < 3) {
                const char* base = (g == 1) ? dpb_lo : dpb_hi;
                af = ldb(base + (l15*17 + k)*16);
            } else {
                af = (bh8){0,0,0,0,0,0,0,0};
            }
            f32x4 wk4 = *(const f32x4*)(wbt + k*80 + g*16);  // weights for D rows 4g..4g+3
#pragma unroll
            for (int j = 0; j < 4; ++j) {
                f32x4 d = mfma16(af, wH[j], zero4);
#pragma unroll
                for (int r = 0; r < 4; ++r)
                    hba[j][r] += wk4[r] * fmaxf(d[r] + of2r[j], 0.0f);
            }
        }
        // hb write: D rows q = 4g+r, cols o = 64wv+16j+l15; bf16 hi | lo halves
#pragma unroll
        for (int j = 0; j < 4; ++j)
#pragma unroll
            for (int r = 0; r < 4; ++r) {
                int q = g*4 + r;
                int o = wv*64 + j*16 + l15;
                float x = hba[j][r];
                u16 h = f2bf(x); u16 l = f2bf(x - bf(h));
                *(u16*)(hbm_ + q*1040 + (size_t)o*2)       = h;
                *(u16*)(hbm_ + q*1040 + 512 + (size_t)o*2) = l;
            }
    }
    __syncthreads();

    // ---- layer2: [16 x 512(hi|lo)] x [512 x 64] via 16 MFMA; B-frags reused for lo half ----
    {
        bh8 bw[8];
#pragma unroll
        for (int ks = 0; ks < 8; ++ks)
            bw[ks] = ldb(cb + (size_t)o_lane*512 + ks*64 + g*16);
        f32x4 acA = zero4, acB = zero4;
#pragma unroll
        for (int ks = 0; ks < 8; ++ks) {
            bh8 a = ldb(hbm_ + l15*1040 + ks*64 + g*16);
            acA = mfma16(a, bw[ks], acA);
        }
#pragma unroll
        for (int ks = 0; ks < 8; ++ks) {
            bh8 a = ldb(hbm_ + l15*1040 + 512 + ks*64 + g*16);
            acB = mfma16(a, bw[ks], acB);
        }
        f32x4 wsb4 = *(const f32x4*)(wsbp + g*16);
#pragma unroll
        for (int r = 0; r < 4; ++r) {
            int q = g*4 + r;
            float pf = acA[r] + acB[r] + b2bo * wsb4[r];
            u16 h = f2bf(pf); u16 l = f2bf(pf - bf(h));
            *(u16*)(dfm + q*784 + (size_t)(128 + o_lane)*2) = h;
            *(u16*)(dfm + q*784 + (size_t)(320 + o_lane)*2) = l;
        }
    }
    __syncthreads();

    // ---- layer 1d: [16 x 384(hi|lo)] x [384 x 64], BN+ReLU epilogue -> h1 (overlays dpb) ----
    {
        bh8 bw[6];
#pragma unroll
        for (int ks = 0; ks < 6; ++ks)
            bw[ks] = ldb(cb + 32768 + (size_t)o_lane*384 + ks*64 + g*16);
        f32x4 acA = zero4, acB = zero4;
#pragma unroll
        for (int ks = 0; ks < 6; ++ks) {
            bh8 a = ldb(dfm + l15*784 + ks*64 + g*16);
            acA = mfma16(a, bw[ks], acA);
        }
#pragma unroll
        for (int ks = 0; ks < 6; ++ks) {
            bh8 a = ldb(dfm + l15*784 + 384 + ks*64 + g*16);
            acB = mfma16(a, bw[ks], acB);
        }
#pragma unroll
        for (int r = 0; r < 4; ++r) {
            int q = g*4 + r;
            float z = (acA[r] + acB[r]) * s1o + o1o;
            z = fmaxf(z, 0.0f);
            u16 h = f2bf(z); u16 l = f2bf(z - bf(h));
            *(u16*)(h1m + q*272 + (size_t)o_lane*2)       = h;
            *(u16*)(h1m + q*272 + 128 + (size_t)o_lane*2) = l;
        }
    }
    __syncthreads();

    // ---- layer 2d: [16 x 128(hi|lo)] x [128 x 64], bias, store ----
    {
        bh8 bw0 = ldb(cb + 57344 + (size_t)o_lane*128 + g*16);
        bh8 bw1 = ldb(cb + 57344 + (size_t)o_lane*128 + 64 + g*16);
        f32x4 ac = zero4;
        { bh8 a = ldb(h1m + l15*272 +   0 + g*16); ac = mfma16(a, bw0, ac); }
        { bh8 a = ldb(h1m + l15*272 +  64 + g*16); ac = mfma16(a, bw1, ac); }
        { bh8 a = ldb(h1m + l15*272 + 128 + g*16); ac = mfma16(a, bw0, ac); }
        { bh8 a = ldb(h1m + l15*272 + 192 + g*16); ac = mfma16(a, bw1, ac); }
#pragma unroll
        for (int r = 0; r < 4; ++r) {
            int q = g*4 + r;
            float ov = ac[r] + b1fo;
            size_t ob = ((size_t)(qbb + q) << 6) + o_lane;
            if (f32) ((float*)outp)[ob] = ov;
            else     ((u16*)outp)[ob]   = f2bf(ov);
        }
    }
}

extern "C" void kernel_launch(void* const* d_in, const int* in_sizes, int n_in,
                              void* d_out, int out_size, void* d_ws, size_t ws_size,
                              hipStream_t stream) {
    const void* pcl   = d_in[0];
    const void* noise = d_in[1];
    const void* feat  = d_in[2];
    const void* w2a   = d_in[3];
    const void* b2a   = d_in[4];
    const void* g2a   = d_in[5];
    const void* bt2a  = d_in[6];
    const void* w2b   = d_in[7];
    const void* b2b   = d_in[8];
    const void* w1a   = d_in[9];
    const void* b1a   = d_in[10];
    const void* g1a   = d_in[11];
    const void* bt1a  = d_in[12];
    const void* w1b   = d_in[13];
    const void* b1b   = d_in[14];

    char* ws = (char*)d_ws;
    float4* pcl4 = (float4*)ws;                    // 128 KB: [B,M] x (x,y,z,sumsq)
    u16* cidx = (u16*)(ws + 131072);               // 32 KB: [B,N]
    u16* knn  = (u16*)(ws + 163840);               // 256 KB: [B,M,16]
    u32* canonb = (u32*)(ws + 425984);             // 64 KB: bf16-pair w2b|w1a|w1b
    // total workspace: 491,520 bytes

    k_canon<<<64,   256, 0, stream>>>(noise, w2b, w1a, w1b, canonb);
    k_prep <<<32,   256, 0, stream>>>(noise, pcl, pcl4);
    k_close<<<1024, 256, 0, stream>>>(pcl4, noise, cidx);
    k_knnh <<<8192, 256, 0, stream>>>(pcl4, knn);
    k_tail <<<1024, 256, 0, stream>>>(pcl4, noise, feat, cidx, knn,
                                      w2a, b2a, g2a, bt2a, canonb, b2b,
                                      b1a, g1a, bt1a, b1b, d_out);
}

// Round 3
// 201.595 us; speedup vs baseline: 1.3791x; 1.3791x over previous
//
#include <hip/hip_runtime.h>
#include <float.h>

typedef unsigned short u16;
typedef unsigned int u32;
typedef unsigned char u8;

typedef float f32x4 __attribute__((ext_vector_type(4)));
typedef short bh8   __attribute__((ext_vector_type(8)));   // 8 bf16 carried as shorts

// B=2, N=8192, M=4096, C=64, K=16, HID=256
__device__ __forceinline__ float bf(u16 u) { return __uint_as_float(((u32)u) << 16); }
__device__ __forceinline__ u16 f2bf(float v) {
    u32 x = __float_as_uint(v);
    u32 r = x + 0x7fffu + ((x >> 16) & 1u);
    return (u16)(r >> 16);
}
// Dtype probe on EVEN u16 positions of a large ~N(0,1) buffer (pcl_noise).
__device__ __forceinline__ int detect_f32(const void* probe) {
    const u16* u = (const u16*)probe;
    u16 v = u[(threadIdx.x & 63) * 2];
    int e = (int)((v >> 7) & 0xFF);
    int moderate = (e >= 100) && (e <= 140);
    return __popcll(__ballot(moderate)) < 48;   // few moderate -> fp32
}
__device__ __forceinline__ float ldv(int f32, const void* p, int i) {
    return f32 ? ((const float*)p)[i] : bf(((const u16*)p)[i]);
}
// fma-chain dot (matches the validated selection math from the passing rounds).
__device__ __forceinline__ float dot3(float x0, float x1, float x2,
                                      float y0, float y1, float y2) {
    return __fmaf_rn(x2, y2, __fmaf_rn(x1, y1, __fmul_rn(x0, y0)));
}
// Monotonic u32 key: ordering on keys == ordering on float distances.
__device__ __forceinline__ u32 mkey32(float d) {
    u32 f = __float_as_uint(d);
    return f ^ (u32)((((int)f) >> 31) | 0x80000000);
}
// 16B LDS/global load as a bf16x8 fragment (bit-pattern carrier).
__device__ __forceinline__ bh8 ldb(const void* p) { return *(const bh8*)p; }
// Guide-verified intrinsic path: A row = lane&15, B col = lane&15,
// D: row = 4*(lane>>4)+reg, col = lane&15 (HW-verified m89 mapping).
// A/B k-slot conventions are identical on both operands, so any HW k-permutation cancels.
__device__ __forceinline__ f32x4 mfma16(bh8 a, bh8 b, f32x4 c) {
    return __builtin_amdgcn_mfma_f32_16x16x32_bf16(a, b, c, 0, 0, 0);
}

// ---- canon: w2b | w1a | w1b packed as BF16 PAIRS (halves the weight stream) ----
__global__ __launch_bounds__(256) void k_canon(const void* __restrict__ probe,
                                               const void* __restrict__ w2b,
                                               const void* __restrict__ w1a,
                                               const void* __restrict__ w1b,
                                               u32* __restrict__ canonb) {
    int f32 = detect_f32(probe);
    int ix = blockIdx.x * 256 + threadIdx.x;       // 0..16383 (pairs)
    const void* src; int j;
    if (ix < 8192)       { src = w2b; j = ix; }          // 64x256 -> 8192 pairs
    else if (ix < 14336) { src = w1a; j = ix - 8192; }   // 64x192 -> 6144 pairs
    else                 { src = w1b; j = ix - 14336; }  // 64x64  -> 2048 pairs
    u32 out;
    if (f32) {
        const float* f = (const float*)src;
        out = ((u32)f2bf(f[2*j+1]) << 16) | (u32)f2bf(f[2*j]);
    } else {
        const u16* su = (const u16*)src;
        out = ((u32)su[2*j+1] << 16) | (u32)su[2*j];
    }
    canonb[ix] = out;
}

// ---- prep: pcl -> float4 (x,y,z,sumsq) ----
__global__ __launch_bounds__(256) void k_prep(const void* __restrict__ probe,
                                              const void* __restrict__ pcl,
                                              float4* __restrict__ pcl4) {
    int f32 = detect_f32(probe);
    int i = blockIdx.x * 256 + threadIdx.x;        // 0..8191
    float x = ldv(f32, pcl, i*3+0), y = ldv(f32, pcl, i*3+1), z = ldv(f32, pcl, i*3+2);
    float s = __fadd_rn(__fadd_rn(__fmul_rn(x,x), __fmul_rn(y,y)), __fmul_rn(z,z));
    pcl4[i] = make_float4(x, y, z, s);
}

// ---- argmin over M for each noise point; 16 lanes per query; 32 KB chunked tile ----
__global__ __launch_bounds__(256) void k_close(const float4* __restrict__ pcl4,
                                               const void* __restrict__ noise,
                                               u16* __restrict__ cidx) {
    __shared__ __align__(16) float4 tile[2048];
    int f32 = detect_f32(noise);
    int t = threadIdx.x, g = t >> 4, s = t & 15;
    int q = blockIdx.x * 16 + g;                   // global noise-point id
    int b = q >> 13;
    const float4* src = pcl4 + ((size_t)b << 12);
    float x0 = ldv(f32, noise, q*3+0), x1 = ldv(f32, noise, q*3+1), x2 = ldv(f32, noise, q*3+2);
    float sx = __fadd_rn(__fadd_rn(__fmul_rn(x0,x0), __fmul_rn(x1,x1)), __fmul_rn(x2,x2));
    float bd = FLT_MAX; int bi = 0;
    for (int ch = 0; ch < 2; ++ch) {
        __syncthreads();
#pragma unroll
        for (int i = 0; i < 8; ++i) { int ix = t + (i << 8); tile[ix] = src[(ch << 11) + ix]; }
        __syncthreads();
        for (int j = 0; j < 128; ++j) {
            int cl = (j << 4) + s;                 // lane-interleaved: conflict-free LDS
            float4 p = tile[cl];
            float dot = dot3(x0, x1, x2, p.x, p.y, p.z);
            float d = __fadd_rn(__fsub_rn(sx, __fmul_rn(2.0f, dot)), p.w);
            int c = (ch << 11) + cl;               // strictly increasing within thread
            if (d < bd) { bd = d; bi = c; }        // -> first-min on ties
        }
    }
#pragma unroll
    for (int m = 8; m >= 1; m >>= 1) {             // lexicographic (d, idx) merge
        float od = __shfl_xor(bd, m);
        int   oi = __shfl_xor(bi, m);
        if (od < bd || (od == bd && oi < bi)) { bd = od; bi = oi; }
    }
    if (s == 0) cidx[q] = (u16)(bi & 4095);        // masked
}

// ---- k_knnh v4: histogram radix-select, ONE BLOCK (4 waves) per query ----
__global__ __launch_bounds__(256) void k_knnh(const float4* __restrict__ pcl4,
                                              u16* __restrict__ knn) {
    __shared__ u8  bins[4096];                     // 4 KB: per-candidate bin cache
    __shared__ u32 hist[256];                      // 1 KB
    __shared__ u32 skey[256];                      // 1 KB survivors
    __shared__ u16 sidx[256];                      // 0.5 KB
    __shared__ float rmn[4], rmx[4];
    __shared__ u32 scnt;
    __shared__ int ibst;
    int t = threadIdx.x, lane = t & 63, wv = t >> 6;
    int q = blockIdx.x;                            // 0..8191
    int b = q >> 12;
    const float4* src = pcl4 + ((size_t)b << 12);
    float4 Q = src[q & 4095];
    float x0 = Q.x, x1 = Q.y, x2 = Q.z, sx = Q.w;
    if (t < 256) hist[t] = 0;                      // zero hist
    if (t == 0) scnt = 0;
    // sample pass: 256 candidates (stride 16) -> block min/max scale estimate
    {
        float4 p = src[t << 4];
        float dot = dot3(x0, x1, x2, p.x, p.y, p.z);
        float d = __fadd_rn(__fsub_rn(sx, __fmul_rn(2.0f, dot)), p.w);
        float mn = d, mx = d;
#pragma unroll
        for (int m = 32; m >= 1; m >>= 1) {
            mn = fminf(mn, __shfl_xor(mn, m));
            mx = fmaxf(mx, __shfl_xor(mx, m));
        }
        if (lane == 0) { rmn[wv] = mn; rmx[wv] = mx; }
    }
    __syncthreads();
    float dmn = fminf(fminf(rmn[0], rmn[1]), fminf(rmn[2], rmn[3]));
    float dmx = fmaxf(fmaxf(rmx[0], rmx[1]), fmaxf(rmx[2], rmx[3]));
    float sc = 1024.0f / fmaxf(dmx - dmn, 1e-20f); // fine bins over lowest quarter
    // hist pass: 16 candidates/thread, bin cached, clamp-bin 255 never counted
#pragma unroll 4
    for (int j = 0; j < 16; ++j) {
        int cin = (j << 8) + t;
        float4 p = src[cin];
        float dot = dot3(x0, x1, x2, p.x, p.y, p.z);
        float d = __fadd_rn(__fsub_rn(sx, __fmul_rn(2.0f, dot)), p.w);
        float fb = fminf(fmaxf((d - dmn) * sc, 0.0f), 255.0f);
        int bn = (int)fb;
        bins[cin] = (u8)bn;
        if (bn < 255) atomicAdd(&hist[bn], 1u);    // no hot-spot
    }
    __syncthreads();
    // prefix over bins 0..254 by wave 0 -> first bin with cum >= 16
    if (t < 64) {
        u32 c0 = hist[4*lane], c1 = hist[4*lane+1];
        u32 c2 = hist[4*lane+2], c3 = hist[4*lane+3];
        u32 loc = c0 + c1 + c2 + c3;
        u32 x = loc;
#pragma unroll
        for (int off = 1; off < 64; off <<= 1) { u32 v = __shfl_up(x, off); if (lane >= off) x += v; }
        u32 excl = x - loc;
        int cand = 999;                            // 999 -> everything survives -> fallback
        if (excl + c0 >= 16u) cand = 4*lane;
        else if (excl + c0 + c1 >= 16u) cand = 4*lane + 1;
        else if (excl + c0 + c1 + c2 >= 16u) cand = 4*lane + 2;
        else if (excl + loc >= 16u) cand = 4*lane + 3;
#pragma unroll
        for (int m = 32; m >= 1; m >>= 1) cand = min(cand, __shfl_xor(cand, m));
        if (lane == 0) ibst = cand;
    }
    __syncthreads();
    int bstar = ibst;
    // gather pass: survivors from the LDS bin cache; reload exact d only for them
#pragma unroll
    for (int j = 0; j < 16; ++j) {
        int cin = (j << 8) + t;
        if ((int)bins[cin] <= bstar) {
            u32 pos = atomicAdd(&scnt, 1u);
            if (pos < 256u) {
                float4 p = src[cin];
                float dot = dot3(x0, x1, x2, p.x, p.y, p.z);
                float d = __fadd_rn(__fsub_rn(sx, __fmul_rn(2.0f, dot)), p.w);
                skey[pos] = mkey32(d);
                sidx[pos] = (u16)cin;
            }
        }
    }
    __syncthreads();
    u32 n = scnt;
    if (n <= 256u) {
        // rank-select: rank = #survivors lex-(key,idx)-smaller; rank<16 -> output
        for (u32 e = (u32)t; e < n; e += 256u) {
            u32 k = skey[e]; u32 i = (u32)sidx[e];
            int rank = 0;
            for (u32 j = 0; j < n; ++j) {
                u32 kj = skey[j]; u32 ij = (u32)sidx[j];
                rank += (kj < k) || (kj == k && ij < i);
            }
            if (rank < 16) knn[((size_t)q << 4) + rank] = (u16)i;
        }
    } else if (t < 64) {
        // exact brute-force fallback on wave 0 (validated ripple + tournament)
        u32 k0=~0u,k1=~0u,k2=~0u,k3=~0u,k4=~0u,k5=~0u,k6=~0u,k7=~0u,
            k8=~0u,k9=~0u,k10=~0u,k11=~0u,k12=~0u,k13=~0u,k14=~0u,k15=~0u;
        u32 i0r=0,i1r=0,i2r=0,i3r=0,i4r=0,i5r=0,i6r=0,i7r=0,
            i8r=0,i9r=0,i10r=0,i11r=0,i12r=0,i13r=0,i14r=0,i15r=0;
        for (int j = 0; j < 64; ++j) {
            int cin = (j << 6) + lane;             // ascending per lane -> stable ties
            float4 p = src[cin];
            float dot = dot3(x0, x1, x2, p.x, p.y, p.z);
            float d = __fadd_rn(__fsub_rn(sx, __fmul_rn(2.0f, dot)), p.w);
            u32 v = mkey32(d); u32 vi = (u32)cin;
            if (v < k15) {
                { u32 c_=(v<k0); u32 nk=c_?v:k0; u32 nv=c_?k0:v; u32 ni=c_?vi:i0r; u32 nj=c_?i0r:vi; k0=nk;i0r=ni;v=nv;vi=nj; }
                { u32 c_=(v<k1); u32 nk=c_?v:k1; u32 nv=c_?k1:v; u32 ni=c_?vi:i1r; u32 nj=c_?i1r:vi; k1=nk;i1r=ni;v=nv;vi=nj; }
                { u32 c_=(v<k2); u32 nk=c_?v:k2; u32 nv=c_?k2:v; u32 ni=c_?vi:i2r; u32 nj=c_?i2r:vi; k2=nk;i2r=ni;v=nv;vi=nj; }
                { u32 c_=(v<k3); u32 nk=c_?v:k3; u32 nv=c_?k3:v; u32 ni=c_?vi:i3r; u32 nj=c_?i3r:vi; k3=nk;i3r=ni;v=nv;vi=nj; }
                { u32 c_=(v<k4); u32 nk=c_?v:k4; u32 nv=c_?k4:v; u32 ni=c_?vi:i4r; u32 nj=c_?i4r:vi; k4=nk;i4r=ni;v=nv;vi=nj; }
                { u32 c_=(v<k5); u32 nk=c_?v:k5; u32 nv=c_?k5:v; u32 ni=c_?vi:i5r; u32 nj=c_?i5r:vi; k5=nk;i5r=ni;v=nv;vi=nj; }
                { u32 c_=(v<k6); u32 nk=c_?v:k6; u32 nv=c_?k6:v; u32 ni=c_?vi:i6r; u32 nj=c_?i6r:vi; k6=nk;i6r=ni;v=nv;vi=nj; }
                { u32 c_=(v<k7); u32 nk=c_?v:k7; u32 nv=c_?k7:v; u32 ni=c_?vi:i7r; u32 nj=c_?i7r:vi; k7=nk;i7r=ni;v=nv;vi=nj; }
                { u32 c_=(v<k8); u32 nk=c_?v:k8; u32 nv=c_?k8:v; u32 ni=c_?vi:i8r; u32 nj=c_?i8r:vi; k8=nk;i8r=ni;v=nv;vi=nj; }
                { u32 c_=(v<k9); u32 nk=c_?v:k9; u32 nv=c_?k9:v; u32 ni=c_?vi:i9r; u32 nj=c_?i9r:vi; k9=nk;i9r=ni;v=nv;vi=nj; }
                { u32 c_=(v<k10); u32 nk=c_?v:k10; u32 nv=c_?k10:v; u32 ni=c_?vi:i10r; u32 nj=c_?i10r:vi; k10=nk;i10r=ni;v=nv;vi=nj; }
                { u32 c_=(v<k11); u32 nk=c_?v:k11; u32 nv=c_?k11:v; u32 ni=c_?vi:i11r; u32 nj=c_?i11r:vi; k11=nk;i11r=ni;v=nv;vi=nj; }
                { u32 c_=(v<k12); u32 nk=c_?v:k12; u32 nv=c_?k12:v; u32 ni=c_?vi:i12r; u32 nj=c_?i12r:vi; k12=nk;i12r=ni;v=nv;vi=nj; }
                { u32 c_=(v<k13); u32 nk=c_?v:k13; u32 nv=c_?k13:v; u32 ni=c_?vi:i13r; u32 nj=c_?i13r:vi; k13=nk;i13r=ni;v=nv;vi=nj; }
                { u32 c_=(v<k14); u32 nk=c_?v:k14; u32 nv=c_?k14:v; u32 ni=c_?vi:i14r; u32 nj=c_?i14r:vi; k14=nk;i14r=ni;v=nv;vi=nj; }
                { u32 c_=(v<k15); u32 nk=c_?v:k15; u32 nv=c_?k15:v; u32 ni=c_?vi:i15r; u32 nj=c_?i15r:vi; k15=nk;i15r=ni;v=nv;vi=nj; }
            }
        }
        u32 myres = 0;
        for (int o = 0; o < 16; ++o) {
            u32 bk = k0, bi2 = i0r;
#pragma unroll
            for (int m = 32; m >= 1; m >>= 1) {
                u32 ok = __shfl_xor(bk, m), oi = __shfl_xor(bi2, m);
                if (ok < bk || (ok == bk && oi < bi2)) { bk = ok; bi2 = oi; }
            }
            if (lane == o) myres = bi2;
            if (k0 == bk && i0r == bi2) {          // winner lane pops its head
                k0=k1; i0r=i1r; k1=k2; i1r=i2r; k2=k3; i2r=i3r; k3=k4; i3r=i4r;
                k4=k5; i4r=i5r; k5=k6; i5r=i6r; k6=k7; i6r=i7r; k7=k8; i7r=i8r;
                k8=k9; i8r=i9r; k9=k10; i9r=i10r; k10=k11; i10r=i11r; k11=k12; i11r=i12r;
                k12=k13; i12r=i13r; k13=k14; i13r=i14r; k14=k15; i14r=i15r;
                k15=~0u; i15r=0xFFFFu;
            }
        }
        if (lane < 16) knn[((size_t)q << 4) + lane] = (u16)myres;
    }
}

// ---- fused tail v5c: all four MLP layers on MFMA (16x16x32 bf16 builtin), 16 q/block.
// v5b -> v5c: NO min-occupancy launch bound (the (256,4) floor forced VGPR=64 and
// spilled ~840 B/thread to scratch: FETCH 125MB / WRITE 215MB, a 268MB runtime
// scratch fill, and 134us runtime).  Also fused the hi/lo passes of layers 2/1d so
// only one B-fragment is live at a time (peak pressure -28 VGPR; identical numerics).
//
// LDS arena layout (bytes):
//   [0,     4352)  dpb_hi : 16 q x 17 slots x 16B  (delta|cp bf16-hi, slot=k, +1 pad slot/row)
//                   ... overlaid later by h1 (16 q x 272B) after dpb is dead
//   [4352,  8704)  dpb_lo : same, bf16-lo residuals
//   [8704,  9984)  wbt    : 16 k x 20 f32 (softmax weights, transposed, padded row)
//   [9984, 10048)  wsb    : 16 f32 (sum-of-weights / den)
//   [10048,10560)  jbuf   : 16 q x 16 u16 neighbor ids
//   [10560,27200)  hb     : 16 q x 1040B (256 bf16 hi | 256 bf16 lo | 16B pad)
//   [27200,39744)  df     : 16 q x 784B  (192 bf16 hi [cf|co|pf] | 192 lo | 16B pad)
__global__ __launch_bounds__(256) void k_tail(const float4* __restrict__ pcl4,
                                              const void* __restrict__ noise,
                                              const void* __restrict__ feat,
                                              const u16* __restrict__ cidx,
                                              const u16* __restrict__ knn,
                                              const void* __restrict__ w2a,
                                              const void* __restrict__ b2a,
                                              const void* __restrict__ g2a,
                                              const void* __restrict__ bt2a,
                                              const u32* __restrict__ canonb,
                                              const void* __restrict__ b2b,
                                              const void* __restrict__ b1a,
                                              const void* __restrict__ g1a,
                                              const void* __restrict__ bt1a,
                                              const void* __restrict__ b1b,
                                              void* __restrict__ outp) {
    __shared__ __align__(16) char arena[39744];
    char* dpb_hi = arena;                 // 4352
    char* dpb_lo = arena + 4352;          // 4352
    char* wbt    = arena + 8704;          // 1280
    char* wsbp   = arena + 9984;          // 64
    u16*  jbuf   = (u16*)(arena + 10048); // 512
    char* hbm_   = arena + 10560;         // 16640
    char* dfm    = arena + 27200;         // 12544
    char* h1m    = arena;                 // overlays dpb_hi (dead after hidden phase)

    int f32 = detect_f32(noise);
    int t = threadIdx.x, lane = t & 63, wv = t >> 6;
    int g = lane >> 4, l15 = lane & 15;
    int qbb = blockIdx.x * 16;
    int o_lane = wv * 16 + l15;           // output channel owned in layers 2/1d/2d
    const float rbn = 1.0f / sqrtf(1.0f + 1e-5f);
    const char* cb = (const char*)canonb;
    const f32x4 zero4 = {0.f, 0.f, 0.f, 0.f};

    // ---- per-lane params: hidden B-frags (w2a * bn_scale; groups 0,1 = hi, group 2 = lo),
    //      of2 per hidden channel, layer-1d/2d scalars ----
    float of2r[4];
    bh8 wH[4];
#pragma unroll
    for (int j = 0; j < 4; ++j) {
        int oh = wv*64 + j*16 + l15;
        float sc = ldv(f32, g2a, oh) * rbn;
        of2r[j] = ldv(f32, b2a, oh) * sc + ldv(f32, bt2a, oh);
        bh8 wz = (bh8){0,0,0,0,0,0,0,0};
        if (g < 3) {
#pragma unroll
            for (int c = 0; c < 6; ++c) {
                float wval = ldv(f32, w2a, oh*6 + c) * sc;
                u16 h = f2bf(wval);
                u16 e = (g == 2) ? f2bf(wval - bf(h)) : h;
                wz[c] = (short)e;
            }
        }
        wH[j] = wz;
    }
    float s1o  = ldv(f32, g1a, o_lane) * rbn;
    float o1o  = ldv(f32, b1a, o_lane) * s1o + ldv(f32, bt1a, o_lane);
    float b2bo = ldv(f32, b2b, o_lane);
    float b1fo = ldv(f32, b1b, o_lane);

    // ---- preamble: per (query, neighbor-slot) delta/cp -> dpb hi/lo, softmax weights ----
    {
        int s = lane & 15;                         // neighbor slot
        int ql = wv*4 + (lane >> 4);               // local query 0..15
        int q = qbb + ql;
        int b = q >> 13;
        int pbase = b << 12;
        int ci = ((int)cidx[q]) & 4095;
        float4 cp = pcl4[pbase + ci];
        float x0 = ldv(f32, noise, q*3+0), x1 = ldv(f32, noise, q*3+1), x2 = ldv(f32, noise, q*3+2);
        float e = 0.0f;
        if (s >= 1) {
            int jk = ((int)knn[(size_t)(pbase + ci) * 16 + s]) & 4095;
            float4 p = pcl4[pbase + jk];
            float d0 = p.x - x0, d1 = p.y - x1, d2 = p.z - x2;
            float dst = sqrtf(__fadd_rn(__fadd_rn(__fmul_rn(d0,d0), __fmul_rn(d1,d1)), __fmul_rn(d2,d2)));
            e = expf(-10.0f * dst);
            float v6[6] = {d0, d1, d2, cp.x, cp.y, cp.z};
            bh8 HW = (bh8){0,0,0,0,0,0,0,0};
            bh8 LW = (bh8){0,0,0,0,0,0,0,0};
#pragma unroll
            for (int c = 0; c < 6; ++c) {
                u16 hh = f2bf(v6[c]);
                u16 ll = f2bf(v6[c] - bf(hh));
                HW[c] = (short)hh;
                LW[c] = (short)ll;
            }
            *(bh8*)(dpb_hi + (ql*17 + s)*16) = HW;
            *(bh8*)(dpb_lo + (ql*17 + s)*16) = LW;
            jbuf[ql*16 + s] = (u16)jk;
        }
        float es = e;
#pragma unroll
        for (int m = 8; m >= 1; m >>= 1) es += __shfl_xor(es, m, 16);
        float den = es + 1e-7f;
        if (s >= 1) *(float*)(wbt + s*80 + ql*4) = e / den;
        if (s == 0) *(float*)(wsbp + ql*4) = es / den;
    }
    __syncthreads();

    // ---- cf/co (lane = feature channel): gather-weighted, write straight into df ----
#pragma unroll
    for (int qq = 0; qq < 4; ++qq) {
        int qloc = wv*4 + qq;
        int q = qbb + qloc;
        int b = q >> 13;
        int pbase = b << 12;
        int ci = ((int)cidx[q]) & 4095;
        size_t fcb = ((size_t)(pbase + ci)) << 6;
        float c0, c1 = 0.0f;
        if (f32) {
            const float* ff = (const float*)feat;
            c0 = ff[fcb + lane];
#pragma unroll
            for (int k = 1; k < 16; ++k) {
                float wk = *(const float*)(wbt + k*80 + qloc*4);
                c1 += wk * ff[(((size_t)(pbase + (int)jbuf[qloc*16 + k])) << 6) + lane];
            }
        } else {
            const u16* fb = (const u16*)feat;
            c0 = bf(fb[fcb + lane]);
#pragma unroll
            for (int k = 1; k < 16; ++k) {
                float wk = *(const float*)(wbt + k*80 + qloc*4);
                c1 += wk * bf(fb[(((size_t)(pbase + (int)jbuf[qloc*16 + k])) << 6) + lane]);
            }
        }
        char* dr = dfm + qloc*784;
        u16 h0 = f2bf(c0); u16 l0 = f2bf(c0 - bf(h0));
        u16 h1v = f2bf(c1); u16 l1v = f2bf(c1 - bf(h1v));
        *(u16*)(dr + (size_t)lane*2)         = h0;   // cf hi (cols 0..63)
        *(u16*)(dr + (size_t)(192+lane)*2)   = l0;   // cf lo
        *(u16*)(dr + (size_t)(64+lane)*2)    = h1v;  // co hi (cols 64..127)
        *(u16*)(dr + (size_t)(256+lane)*2)   = l1v;  // co lo
    }

    // ---- hidden layer on MFMA: A rows = queries (l15); k-groups g0=hi(x),g1=lo(x),g2=hi(x),g3=0;
    //      B groups g0,g1 = hi(w*sc), g2 = lo(w*sc), g3 = 0  =>  x*w to ~2^-16 rel.
    //      Per-k BN+ReLU epilogue, wk-weighted sum into hb. ----
    {
        f32x4 hba[4];
#pragma unroll
        for (int j = 0; j < 4; ++j) hba[j] = zero4;
#pragma unroll
        for (int k = 1; k < 16; ++k) {
            bh8 af;
            if (g < 3) {
                const char* base = (g == 1) ? dpb_lo : dpb_hi;
                af = ldb(base + (l15*17 + k)*16);
            } else {
                af = (bh8){0,0,0,0,0,0,0,0};
            }
            f32x4 wk4 = *(const f32x4*)(wbt + k*80 + g*16);  // weights for D rows 4g..4g+3
#pragma unroll
            for (int j = 0; j < 4; ++j) {
                f32x4 d = mfma16(af, wH[j], zero4);
#pragma unroll
                for (int r = 0; r < 4; ++r)
                    hba[j][r] += wk4[r] * fmaxf(d[r] + of2r[j], 0.0f);
            }
        }
        // hb write: D rows q = 4g+r, cols o = 64wv+16j+l15; bf16 hi | lo halves
#pragma unroll
        for (int j = 0; j < 4; ++j)
#pragma unroll
            for (int r = 0; r < 4; ++r) {
                int q = g*4 + r;
                int o = wv*64 + j*16 + l15;
                float x = hba[j][r];
                u16 h = f2bf(x); u16 l = f2bf(x - bf(h));
                *(u16*)(hbm_ + q*1040 + (size_t)o*2)       = h;
                *(u16*)(hbm_ + q*1040 + 512 + (size_t)o*2) = l;
            }
    }
    __syncthreads();

    // ---- layer2: [16 x 512(hi|lo)] x [512 x 64]; hi/lo fused per ks: one bw live ----
    {
        f32x4 acA = zero4, acB = zero4;
#pragma unroll
        for (int ks = 0; ks < 8; ++ks) {
            bh8 bw = ldb(cb + (size_t)o_lane*512 + ks*64 + g*16);
            bh8 aH = ldb(hbm_ + l15*1040 + ks*64 + g*16);
            bh8 aL = ldb(hbm_ + l15*1040 + 512 + ks*64 + g*16);
            acA = mfma16(aH, bw, acA);
            acB = mfma16(aL, bw, acB);
        }
        f32x4 wsb4 = *(const f32x4*)(wsbp + g*16);
#pragma unroll
        for (int r = 0; r < 4; ++r) {
            int q = g*4 + r;
            float pf = acA[r] + acB[r] + b2bo * wsb4[r];
            u16 h = f2bf(pf); u16 l = f2bf(pf - bf(h));
            *(u16*)(dfm + q*784 + (size_t)(128 + o_lane)*2) = h;
            *(u16*)(dfm + q*784 + (size_t)(320 + o_lane)*2) = l;
        }
    }
    __syncthreads();

    // ---- layer 1d: [16 x 384(hi|lo)] x [384 x 64], fused hi/lo, BN+ReLU -> h1 (overlays dpb) ----
    {
        f32x4 acA = zero4, acB = zero4;
#pragma unroll
        for (int ks = 0; ks < 6; ++ks) {
            bh8 bw = ldb(cb + 32768 + (size_t)o_lane*384 + ks*64 + g*16);
            bh8 aH = ldb(dfm + l15*784 + ks*64 + g*16);
            bh8 aL = ldb(dfm + l15*784 + 384 + ks*64 + g*16);
            acA = mfma16(aH, bw, acA);
            acB = mfma16(aL, bw, acB);
        }
#pragma unroll
        for (int r = 0; r < 4; ++r) {
            int q = g*4 + r;
            float z = (acA[r] + acB[r]) * s1o + o1o;
            z = fmaxf(z, 0.0f);
            u16 h = f2bf(z); u16 l = f2bf(z - bf(h));
            *(u16*)(h1m + q*272 + (size_t)o_lane*2)       = h;
            *(u16*)(h1m + q*272 + 128 + (size_t)o_lane*2) = l;
        }
    }
    __syncthreads();

    // ---- layer 2d: [16 x 128(hi|lo)] x [128 x 64], bias, store ----
    {
        bh8 bw0 = ldb(cb + 57344 + (size_t)o_lane*128 + g*16);
        bh8 bw1 = ldb(cb + 57344 + (size_t)o_lane*128 + 64 + g*16);
        f32x4 ac = zero4;
        { bh8 a = ldb(h1m + l15*272 +   0 + g*16); ac = mfma16(a, bw0, ac); }
        { bh8 a = ldb(h1m + l15*272 +  64 + g*16); ac = mfma16(a, bw1, ac); }
        { bh8 a = ldb(h1m + l15*272 + 128 + g*16); ac = mfma16(a, bw0, ac); }
        { bh8 a = ldb(h1m + l15*272 + 192 + g*16); ac = mfma16(a, bw1, ac); }
#pragma unroll
        for (int r = 0; r < 4; ++r) {
            int q = g*4 + r;
            float ov = ac[r] + b1fo;
            size_t ob = ((size_t)(qbb + q) << 6) + o_lane;
            if (f32) ((float*)outp)[ob] = ov;
            else     ((u16*)outp)[ob]   = f2bf(ov);
        }
    }
}

extern "C" void kernel_launch(void* const* d_in, const int* in_sizes, int n_in,
                              void* d_out, int out_size, void* d_ws, size_t ws_size,
                              hipStream_t stream) {
    const void* pcl   = d_in[0];
    const void* noise = d_in[1];
    const void* feat  = d_in[2];
    const void* w2a   = d_in[3];
    const void* b2a   = d_in[4];
    const void* g2a   = d_in[5];
    const void* bt2a  = d_in[6];
    const void* w2b   = d_in[7];
    const void* b2b   = d_in[8];
    const void* w1a   = d_in[9];
    const void* b1a   = d_in[10];
    const void* g1a   = d_in[11];
    const void* bt1a  = d_in[12];
    const void* w1b   = d_in[13];
    const void* b1b   = d_in[14];

    char* ws = (char*)d_ws;
    float4* pcl4 = (float4*)ws;                    // 128 KB: [B,M] x (x,y,z,sumsq)
    u16* cidx = (u16*)(ws + 131072);               // 32 KB: [B,N]
    u16* knn  = (u16*)(ws + 163840);               // 256 KB: [B,M,16]
    u32* canonb = (u32*)(ws + 425984);             // 64 KB: bf16-pair w2b|w1a|w1b
    // total workspace: 491,520 bytes

    k_canon<<<64,   256, 0, stream>>>(noise, w2b, w1a, w1b, canonb);
    k_prep <<<32,   256, 0, stream>>>(noise, pcl, pcl4);
    k_close<<<1024, 256, 0, stream>>>(pcl4, noise, cidx);
    k_knnh <<<8192, 256, 0, stream>>>(pcl4, knn);
    k_tail <<<1024, 256, 0, stream>>>(pcl4, noise, feat, cidx, knn,
                                      w2a, b2a, g2a, bt2a, canonb, b2b,
                                      b1a, g1a, bt1a, b1b, d_out);
}

// Round 4
// 200.380 us; speedup vs baseline: 1.3875x; 1.0061x over previous
//
#include <hip/hip_runtime.h>
#include <float.h>

typedef unsigned short u16;
typedef unsigned int u32;
typedef unsigned char u8;

typedef float f32x4 __attribute__((ext_vector_type(4)));
typedef short bh8   __attribute__((ext_vector_type(8)));   // 8 bf16 carried as shorts

// B=2, N=8192, M=4096, C=64, K=16, HID=256
__device__ __forceinline__ float bf(u16 u) { return __uint_as_float(((u32)u) << 16); }
__device__ __forceinline__ u16 f2bf(float v) {
    u32 x = __float_as_uint(v);
    u32 r = x + 0x7fffu + ((x >> 16) & 1u);
    return (u16)(r >> 16);
}
// Dtype probe on EVEN u16 positions of a large ~N(0,1) buffer (pcl_noise).
__device__ __forceinline__ int detect_f32(const void* probe) {
    const u16* u = (const u16*)probe;
    u16 v = u[(threadIdx.x & 63) * 2];
    int e = (int)((v >> 7) & 0xFF);
    int moderate = (e >= 100) && (e <= 140);
    return __popcll(__ballot(moderate)) < 48;   // few moderate -> fp32
}
__device__ __forceinline__ float ldv(int f32, const void* p, int i) {
    return f32 ? ((const float*)p)[i] : bf(((const u16*)p)[i]);
}
// fma-chain dot (matches the validated selection math from the passing rounds).
__device__ __forceinline__ float dot3(float x0, float x1, float x2,
                                      float y0, float y1, float y2) {
    return __fmaf_rn(x2, y2, __fmaf_rn(x1, y1, __fmul_rn(x0, y0)));
}
// Monotonic u32 key: ordering on keys == ordering on float distances.
__device__ __forceinline__ u32 mkey32(float d) {
    u32 f = __float_as_uint(d);
    return f ^ (u32)((((int)f) >> 31) | 0x80000000);
}
// 16B LDS/global load as a bf16x8 fragment (bit-pattern carrier).
__device__ __forceinline__ bh8 ldb(const void* p) { return *(const bh8*)p; }
// Guide-verified intrinsic path: A row = lane&15, B col = lane&15,
// D: row = 4*(lane>>4)+reg, col = lane&15 (HW-verified m89 mapping).
// A/B k-slot conventions are identical on both operands, so any HW k-permutation cancels.
__device__ __forceinline__ f32x4 mfma16(bh8 a, bh8 b, f32x4 c) {
    return __builtin_amdgcn_mfma_f32_16x16x32_bf16(a, b, c, 0, 0, 0);
}

// ---- pre: (merged canon+prep, saves one serialized launch) ----
// blocks 0..63  : w2b | w1a | w1b packed as BF16 PAIRS into canonb
// blocks 64..95 : pcl -> float4 (x,y,z,sumsq)
__global__ __launch_bounds__(256) void k_pre(const void* __restrict__ probe,
                                             const void* __restrict__ w2b,
                                             const void* __restrict__ w1a,
                                             const void* __restrict__ w1b,
                                             u32* __restrict__ canonb,
                                             const void* __restrict__ pcl,
                                             float4* __restrict__ pcl4) {
    int f32 = detect_f32(probe);
    int bx = blockIdx.x, t = threadIdx.x;
    if (bx < 64) {
        int ix = bx * 256 + t;                     // 0..16383 (pairs)
        const void* src; int j;
        if (ix < 8192)       { src = w2b; j = ix; }          // 64x256 -> 8192 pairs
        else if (ix < 14336) { src = w1a; j = ix - 8192; }   // 64x192 -> 6144 pairs
        else                 { src = w1b; j = ix - 14336; }  // 64x64  -> 2048 pairs
        u32 out;
        if (f32) {
            const float* f = (const float*)src;
            out = ((u32)f2bf(f[2*j+1]) << 16) | (u32)f2bf(f[2*j]);
        } else {
            const u16* su = (const u16*)src;
            out = ((u32)su[2*j+1] << 16) | (u32)su[2*j];
        }
        canonb[ix] = out;
    } else {
        int i = (bx - 64) * 256 + t;               // 0..8191
        float x = ldv(f32, pcl, i*3+0), y = ldv(f32, pcl, i*3+1), z = ldv(f32, pcl, i*3+2);
        float s = __fadd_rn(__fadd_rn(__fmul_rn(x,x), __fmul_rn(y,y)), __fmul_rn(z,z));
        pcl4[i] = make_float4(x, y, z, s);
    }
}

// ---- argmin over M for each noise point; 16 lanes per query; 32 KB chunked tile ----
__global__ __launch_bounds__(256) void k_close(const float4* __restrict__ pcl4,
                                               const void* __restrict__ noise,
                                               u16* __restrict__ cidx) {
    __shared__ __align__(16) float4 tile[2048];
    int f32 = detect_f32(noise);
    int t = threadIdx.x, g = t >> 4, s = t & 15;
    int q = blockIdx.x * 16 + g;                   // global noise-point id
    int b = q >> 13;
    const float4* src = pcl4 + ((size_t)b << 12);
    float x0 = ldv(f32, noise, q*3+0), x1 = ldv(f32, noise, q*3+1), x2 = ldv(f32, noise, q*3+2);
    float sx = __fadd_rn(__fadd_rn(__fmul_rn(x0,x0), __fmul_rn(x1,x1)), __fmul_rn(x2,x2));
    float bd = FLT_MAX; int bi = 0;
    for (int ch = 0; ch < 2; ++ch) {
        __syncthreads();
#pragma unroll
        for (int i = 0; i < 8; ++i) { int ix = t + (i << 8); tile[ix] = src[(ch << 11) + ix]; }
        __syncthreads();
        for (int j = 0; j < 128; ++j) {
            int cl = (j << 4) + s;                 // lane-interleaved: conflict-free LDS
            float4 p = tile[cl];
            float dot = dot3(x0, x1, x2, p.x, p.y, p.z);
            float d = __fadd_rn(__fsub_rn(sx, __fmul_rn(2.0f, dot)), p.w);
            int c = (ch << 11) + cl;               // strictly increasing within thread
            if (d < bd) { bd = d; bi = c; }        // -> first-min on ties
        }
    }
#pragma unroll
    for (int m = 8; m >= 1; m >>= 1) {             // lexicographic (d, idx) merge
        float od = __shfl_xor(bd, m);
        int   oi = __shfl_xor(bi, m);
        if (od < bd || (od == bd && oi < bi)) { bd = od; bi = oi; }
    }
    if (s == 0) cidx[q] = (u16)(bi & 4095);        // masked
}

// ---- k_knnh v4: histogram radix-select, ONE BLOCK (4 waves) per query ----
__global__ __launch_bounds__(256) void k_knnh(const float4* __restrict__ pcl4,
                                              u16* __restrict__ knn) {
    __shared__ u8  bins[4096];                     // 4 KB: per-candidate bin cache
    __shared__ u32 hist[256];                      // 1 KB
    __shared__ u32 skey[256];                      // 1 KB survivors
    __shared__ u16 sidx[256];                      // 0.5 KB
    __shared__ float rmn[4], rmx[4];
    __shared__ u32 scnt;
    __shared__ int ibst;
    int t = threadIdx.x, lane = t & 63, wv = t >> 6;
    int q = blockIdx.x;                            // 0..8191
    int b = q >> 12;
    const float4* src = pcl4 + ((size_t)b << 12);
    float4 Q = src[q & 4095];
    float x0 = Q.x, x1 = Q.y, x2 = Q.z, sx = Q.w;
    if (t < 256) hist[t] = 0;                      // zero hist
    if (t == 0) scnt = 0;
    // sample pass: 256 candidates (stride 16) -> block min/max scale estimate
    {
        float4 p = src[t << 4];
        float dot = dot3(x0, x1, x2, p.x, p.y, p.z);
        float d = __fadd_rn(__fsub_rn(sx, __fmul_rn(2.0f, dot)), p.w);
        float mn = d, mx = d;
#pragma unroll
        for (int m = 32; m >= 1; m >>= 1) {
            mn = fminf(mn, __shfl_xor(mn, m));
            mx = fmaxf(mx, __shfl_xor(mx, m));
        }
        if (lane == 0) { rmn[wv] = mn; rmx[wv] = mx; }
    }
    __syncthreads();
    float dmn = fminf(fminf(rmn[0], rmn[1]), fminf(rmn[2], rmn[3]));
    float dmx = fmaxf(fmaxf(rmx[0], rmx[1]), fmaxf(rmx[2], rmx[3]));
    float sc = 1024.0f / fmaxf(dmx - dmn, 1e-20f); // fine bins over lowest quarter
    // hist pass: 16 candidates/thread, bin cached, clamp-bin 255 never counted
#pragma unroll 4
    for (int j = 0; j < 16; ++j) {
        int cin = (j << 8) + t;
        float4 p = src[cin];
        float dot = dot3(x0, x1, x2, p.x, p.y, p.z);
        float d = __fadd_rn(__fsub_rn(sx, __fmul_rn(2.0f, dot)), p.w);
        float fb = fminf(fmaxf((d - dmn) * sc, 0.0f), 255.0f);
        int bn = (int)fb;
        bins[cin] = (u8)bn;
        if (bn < 255) atomicAdd(&hist[bn], 1u);    // no hot-spot
    }
    __syncthreads();
    // prefix over bins 0..254 by wave 0 -> first bin with cum >= 16
    if (t < 64) {
        u32 c0 = hist[4*lane], c1 = hist[4*lane+1];
        u32 c2 = hist[4*lane+2], c3 = hist[4*lane+3];
        u32 loc = c0 + c1 + c2 + c3;
        u32 x = loc;
#pragma unroll
        for (int off = 1; off < 64; off <<= 1) { u32 v = __shfl_up(x, off); if (lane >= off) x += v; }
        u32 excl = x - loc;
        int cand = 999;                            // 999 -> everything survives -> fallback
        if (excl + c0 >= 16u) cand = 4*lane;
        else if (excl + c0 + c1 >= 16u) cand = 4*lane + 1;
        else if (excl + c0 + c1 + c2 >= 16u) cand = 4*lane + 2;
        else if (excl + loc >= 16u) cand = 4*lane + 3;
#pragma unroll
        for (int m = 32; m >= 1; m >>= 1) cand = min(cand, __shfl_xor(cand, m));
        if (lane == 0) ibst = cand;
    }
    __syncthreads();
    int bstar = ibst;
    // gather pass: survivors from the LDS bin cache; reload exact d only for them
#pragma unroll
    for (int j = 0; j < 16; ++j) {
        int cin = (j << 8) + t;
        if ((int)bins[cin] <= bstar) {
            u32 pos = atomicAdd(&scnt, 1u);
            if (pos < 256u) {
                float4 p = src[cin];
                float dot = dot3(x0, x1, x2, p.x, p.y, p.z);
                float d = __fadd_rn(__fsub_rn(sx, __fmul_rn(2.0f, dot)), p.w);
                skey[pos] = mkey32(d);
                sidx[pos] = (u16)cin;
            }
        }
    }
    __syncthreads();
    u32 n = scnt;
    if (n <= 256u) {
        // rank-select: rank = #survivors lex-(key,idx)-smaller; rank<16 -> output
        for (u32 e = (u32)t; e < n; e += 256u) {
            u32 k = skey[e]; u32 i = (u32)sidx[e];
            int rank = 0;
            for (u32 j = 0; j < n; ++j) {
                u32 kj = skey[j]; u32 ij = (u32)sidx[j];
                rank += (kj < k) || (kj == k && ij < i);
            }
            if (rank < 16) knn[((size_t)q << 4) + rank] = (u16)i;
        }
    } else if (t < 64) {
        // exact brute-force fallback on wave 0 (validated ripple + tournament)
        u32 k0=~0u,k1=~0u,k2=~0u,k3=~0u,k4=~0u,k5=~0u,k6=~0u,k7=~0u,
            k8=~0u,k9=~0u,k10=~0u,k11=~0u,k12=~0u,k13=~0u,k14=~0u,k15=~0u;
        u32 i0r=0,i1r=0,i2r=0,i3r=0,i4r=0,i5r=0,i6r=0,i7r=0,
            i8r=0,i9r=0,i10r=0,i11r=0,i12r=0,i13r=0,i14r=0,i15r=0;
        for (int j = 0; j < 64; ++j) {
            int cin = (j << 6) + lane;             // ascending per lane -> stable ties
            float4 p = src[cin];
            float dot = dot3(x0, x1, x2, p.x, p.y, p.z);
            float d = __fadd_rn(__fsub_rn(sx, __fmul_rn(2.0f, dot)), p.w);
            u32 v = mkey32(d); u32 vi = (u32)cin;
            if (v < k15) {
                { u32 c_=(v<k0); u32 nk=c_?v:k0; u32 nv=c_?k0:v; u32 ni=c_?vi:i0r; u32 nj=c_?i0r:vi; k0=nk;i0r=ni;v=nv;vi=nj; }
                { u32 c_=(v<k1); u32 nk=c_?v:k1; u32 nv=c_?k1:v; u32 ni=c_?vi:i1r; u32 nj=c_?i1r:vi; k1=nk;i1r=ni;v=nv;vi=nj; }
                { u32 c_=(v<k2); u32 nk=c_?v:k2; u32 nv=c_?k2:v; u32 ni=c_?vi:i2r; u32 nj=c_?i2r:vi; k2=nk;i2r=ni;v=nv;vi=nj; }
                { u32 c_=(v<k3); u32 nk=c_?v:k3; u32 nv=c_?k3:v; u32 ni=c_?vi:i3r; u32 nj=c_?i3r:vi; k3=nk;i3r=ni;v=nv;vi=nj; }
                { u32 c_=(v<k4); u32 nk=c_?v:k4; u32 nv=c_?k4:v; u32 ni=c_?vi:i4r; u32 nj=c_?i4r:vi; k4=nk;i4r=ni;v=nv;vi=nj; }
                { u32 c_=(v<k5); u32 nk=c_?v:k5; u32 nv=c_?k5:v; u32 ni=c_?vi:i5r; u32 nj=c_?i5r:vi; k5=nk;i5r=ni;v=nv;vi=nj; }
                { u32 c_=(v<k6); u32 nk=c_?v:k6; u32 nv=c_?k6:v; u32 ni=c_?vi:i6r; u32 nj=c_?i6r:vi; k6=nk;i6r=ni;v=nv;vi=nj; }
                { u32 c_=(v<k7); u32 nk=c_?v:k7; u32 nv=c_?k7:v; u32 ni=c_?vi:i7r; u32 nj=c_?i7r:vi; k7=nk;i7r=ni;v=nv;vi=nj; }
                { u32 c_=(v<k8); u32 nk=c_?v:k8; u32 nv=c_?k8:v; u32 ni=c_?vi:i8r; u32 nj=c_?i8r:vi; k8=nk;i8r=ni;v=nv;vi=nj; }
                { u32 c_=(v<k9); u32 nk=c_?v:k9; u32 nv=c_?k9:v; u32 ni=c_?vi:i9r; u32 nj=c_?i9r:vi; k9=nk;i9r=ni;v=nv;vi=nj; }
                { u32 c_=(v<k10); u32 nk=c_?v:k10; u32 nv=c_?k10:v; u32 ni=c_?vi:i10r; u32 nj=c_?i10r:vi; k10=nk;i10r=ni;v=nv;vi=nj; }
                { u32 c_=(v<k11); u32 nk=c_?v:k11; u32 nv=c_?k11:v; u32 ni=c_?vi:i11r; u32 nj=c_?i11r:vi; k11=nk;i11r=ni;v=nv;vi=nj; }
                { u32 c_=(v<k12); u32 nk=c_?v:k12; u32 nv=c_?k12:v; u32 ni=c_?vi:i12r; u32 nj=c_?i12r:vi; k12=nk;i12r=ni;v=nv;vi=nj; }
                { u32 c_=(v<k13); u32 nk=c_?v:k13; u32 nv=c_?k13:v; u32 ni=c_?vi:i13r; u32 nj=c_?i13r:vi; k13=nk;i13r=ni;v=nv;vi=nj; }
                { u32 c_=(v<k14); u32 nk=c_?v:k14; u32 nv=c_?k14:v; u32 ni=c_?vi:i14r; u32 nj=c_?i14r:vi; k14=nk;i14r=ni;v=nv;vi=nj; }
                { u32 c_=(v<k15); u32 nk=c_?v:k15; u32 nv=c_?k15:v; u32 ni=c_?vi:i15r; u32 nj=c_?i15r:vi; k15=nk;i15r=ni;v=nv;vi=nj; }
            }
        }
        u32 myres = 0;
        for (int o = 0; o < 16; ++o) {
            u32 bk = k0, bi2 = i0r;
#pragma unroll
            for (int m = 32; m >= 1; m >>= 1) {
                u32 ok = __shfl_xor(bk, m), oi = __shfl_xor(bi2, m);
                if (ok < bk || (ok == bk && oi < bi2)) { bk = ok; bi2 = oi; }
            }
            if (lane == o) myres = bi2;
            if (k0 == bk && i0r == bi2) {          // winner lane pops its head
                k0=k1; i0r=i1r; k1=k2; i1r=i2r; k2=k3; i2r=i3r; k3=k4; i3r=i4r;
                k4=k5; i4r=i5r; k5=k6; i5r=i6r; k6=k7; i6r=i7r; k7=k8; i7r=i8r;
                k8=k9; i8r=i9r; k9=k10; i9r=i10r; k10=k11; i10r=i11r; k11=k12; i11r=i12r;
                k12=k13; i12r=i13r; k13=k14; i13r=i14r; k14=k15; i14r=i15r;
                k15=~0u; i15r=0xFFFFu;
            }
        }
        if (lane < 16) knn[((size_t)q << 4) + lane] = (u16)myres;
    }
}

// ---- fused tail v5d: v5c + VGPR-pressure fix.  Round-3 counters: VGPR=252 ->
// 2 waves/SIMD -> 2 blk/CU, all pipes idle (MfmaUtil 2.7, VALU 17, HBM 2%):
// latency-bound on occupancy.  Cause: full unroll of the MFMA loops let the
// scheduler hoist ALL ds_reads (hidden: 15x12 VGPR; layer2: 8x24).  Fix:
// #pragma unroll 2 on those loops (identical accumulation order, ~1/4 the live
// values).  Target VGPR <=128 -> 4 blk/CU (LDS 39936x4 = 156KB fits).
//
// LDS arena layout (bytes):
//   [0,     4352)  dpb_hi : 16 q x 17 slots x 16B  (delta|cp bf16-hi, slot=k, +1 pad slot/row)
//                   ... overlaid later by h1 (16 q x 272B) after dpb is dead
//   [4352,  8704)  dpb_lo : same, bf16-lo residuals
//   [8704,  9984)  wbt    : 16 k x 20 f32 (softmax weights, transposed, padded row)
//   [9984, 10048)  wsb    : 16 f32 (sum-of-weights / den)
//   [10048,10560)  jbuf   : 16 q x 16 u16 neighbor ids
//   [10560,27200)  hb     : 16 q x 1040B (256 bf16 hi | 256 bf16 lo | 16B pad)
//   [27200,39744)  df     : 16 q x 784B  (192 bf16 hi [cf|co|pf] | 192 lo | 16B pad)
__global__ __launch_bounds__(256) void k_tail(const float4* __restrict__ pcl4,
                                              const void* __restrict__ noise,
                                              const void* __restrict__ feat,
                                              const u16* __restrict__ cidx,
                                              const u16* __restrict__ knn,
                                              const void* __restrict__ w2a,
                                              const void* __restrict__ b2a,
                                              const void* __restrict__ g2a,
                                              const void* __restrict__ bt2a,
                                              const u32* __restrict__ canonb,
                                              const void* __restrict__ b2b,
                                              const void* __restrict__ b1a,
                                              const void* __restrict__ g1a,
                                              const void* __restrict__ bt1a,
                                              const void* __restrict__ b1b,
                                              void* __restrict__ outp) {
    __shared__ __align__(16) char arena[39744];
    char* dpb_hi = arena;                 // 4352
    char* dpb_lo = arena + 4352;          // 4352
    char* wbt    = arena + 8704;          // 1280
    char* wsbp   = arena + 9984;          // 64
    u16*  jbuf   = (u16*)(arena + 10048); // 512
    char* hbm_   = arena + 10560;         // 16640
    char* dfm    = arena + 27200;         // 12544
    char* h1m    = arena;                 // overlays dpb_hi (dead after hidden phase)

    int f32 = detect_f32(noise);
    int t = threadIdx.x, lane = t & 63, wv = t >> 6;
    int g = lane >> 4, l15 = lane & 15;
    int qbb = blockIdx.x * 16;
    int o_lane = wv * 16 + l15;           // output channel owned in layers 2/1d/2d
    const float rbn = 1.0f / sqrtf(1.0f + 1e-5f);
    const char* cb = (const char*)canonb;
    const f32x4 zero4 = {0.f, 0.f, 0.f, 0.f};

    // ---- per-lane params: hidden B-frags (w2a * bn_scale; groups 0,1 = hi, group 2 = lo),
    //      of2 per hidden channel, layer-1d/2d scalars ----
    float of2r[4];
    bh8 wH[4];
#pragma unroll
    for (int j = 0; j < 4; ++j) {
        int oh = wv*64 + j*16 + l15;
        float sc = ldv(f32, g2a, oh) * rbn;
        of2r[j] = ldv(f32, b2a, oh) * sc + ldv(f32, bt2a, oh);
        bh8 wz = (bh8){0,0,0,0,0,0,0,0};
        if (g < 3) {
#pragma unroll
            for (int c = 0; c < 6; ++c) {
                float wval = ldv(f32, w2a, oh*6 + c) * sc;
                u16 h = f2bf(wval);
                u16 e = (g == 2) ? f2bf(wval - bf(h)) : h;
                wz[c] = (short)e;
            }
        }
        wH[j] = wz;
    }
    float s1o  = ldv(f32, g1a, o_lane) * rbn;
    float o1o  = ldv(f32, b1a, o_lane) * s1o + ldv(f32, bt1a, o_lane);
    float b2bo = ldv(f32, b2b, o_lane);
    float b1fo = ldv(f32, b1b, o_lane);

    // ---- preamble: per (query, neighbor-slot) delta/cp -> dpb hi/lo, softmax weights ----
    {
        int s = lane & 15;                         // neighbor slot
        int ql = wv*4 + (lane >> 4);               // local query 0..15
        int q = qbb + ql;
        int b = q >> 13;
        int pbase = b << 12;
        int ci = ((int)cidx[q]) & 4095;
        float4 cp = pcl4[pbase + ci];
        float x0 = ldv(f32, noise, q*3+0), x1 = ldv(f32, noise, q*3+1), x2 = ldv(f32, noise, q*3+2);
        float e = 0.0f;
        if (s >= 1) {
            int jk = ((int)knn[(size_t)(pbase + ci) * 16 + s]) & 4095;
            float4 p = pcl4[pbase + jk];
            float d0 = p.x - x0, d1 = p.y - x1, d2 = p.z - x2;
            float dst = sqrtf(__fadd_rn(__fadd_rn(__fmul_rn(d0,d0), __fmul_rn(d1,d1)), __fmul_rn(d2,d2)));
            e = expf(-10.0f * dst);
            float v6[6] = {d0, d1, d2, cp.x, cp.y, cp.z};
            bh8 HW = (bh8){0,0,0,0,0,0,0,0};
            bh8 LW = (bh8){0,0,0,0,0,0,0,0};
#pragma unroll
            for (int c = 0; c < 6; ++c) {
                u16 hh = f2bf(v6[c]);
                u16 ll = f2bf(v6[c] - bf(hh));
                HW[c] = (short)hh;
                LW[c] = (short)ll;
            }
            *(bh8*)(dpb_hi + (ql*17 + s)*16) = HW;
            *(bh8*)(dpb_lo + (ql*17 + s)*16) = LW;
            jbuf[ql*16 + s] = (u16)jk;
        }
        float es = e;
#pragma unroll
        for (int m = 8; m >= 1; m >>= 1) es += __shfl_xor(es, m, 16);
        float den = es + 1e-7f;
        if (s >= 1) *(float*)(wbt + s*80 + ql*4) = e / den;
        if (s == 0) *(float*)(wsbp + ql*4) = es / den;
    }
    __syncthreads();

    // ---- cf/co (lane = feature channel): gather-weighted, write straight into df ----
#pragma unroll
    for (int qq = 0; qq < 4; ++qq) {
        int qloc = wv*4 + qq;
        int q = qbb + qloc;
        int b = q >> 13;
        int pbase = b << 13;
        pbase = (q >> 13) << 12;
        int ci = ((int)cidx[q]) & 4095;
        size_t fcb = ((size_t)(pbase + ci)) << 6;
        float c0, c1 = 0.0f;
        if (f32) {
            const float* ff = (const float*)feat;
            c0 = ff[fcb + lane];
#pragma unroll
            for (int k = 1; k < 16; ++k) {
                float wk = *(const float*)(wbt + k*80 + qloc*4);
                c1 += wk * ff[(((size_t)(pbase + (int)jbuf[qloc*16 + k])) << 6) + lane];
            }
        } else {
            const u16* fb = (const u16*)feat;
            c0 = bf(fb[fcb + lane]);
#pragma unroll
            for (int k = 1; k < 16; ++k) {
                float wk = *(const float*)(wbt + k*80 + qloc*4);
                c1 += wk * bf(fb[(((size_t)(pbase + (int)jbuf[qloc*16 + k])) << 6) + lane]);
            }
        }
        char* dr = dfm + qloc*784;
        u16 h0 = f2bf(c0); u16 l0 = f2bf(c0 - bf(h0));
        u16 h1v = f2bf(c1); u16 l1v = f2bf(c1 - bf(h1v));
        *(u16*)(dr + (size_t)lane*2)         = h0;   // cf hi (cols 0..63)
        *(u16*)(dr + (size_t)(192+lane)*2)   = l0;   // cf lo
        *(u16*)(dr + (size_t)(64+lane)*2)    = h1v;  // co hi (cols 64..127)
        *(u16*)(dr + (size_t)(256+lane)*2)   = l1v;  // co lo
    }

    // ---- hidden layer on MFMA: A rows = queries (l15); k-groups g0=hi(x),g1=lo(x),g2=hi(x),g3=0;
    //      B groups g0,g1 = hi(w*sc), g2 = lo(w*sc), g3 = 0  =>  x*w to ~2^-16 rel.
    //      Per-k BN+ReLU epilogue, wk-weighted sum into hb.
    //      unroll 2 (NOT full): caps live ds_read values; same accumulation order. ----
    {
        f32x4 hba[4];
#pragma unroll
        for (int j = 0; j < 4; ++j) hba[j] = zero4;
#pragma unroll 2
        for (int k = 1; k < 16; ++k) {
            bh8 af;
            if (g < 3) {
                const char* base = (g == 1) ? dpb_lo : dpb_hi;
                af = ldb(base + (l15*17 + k)*16);
            } else {
                af = (bh8){0,0,0,0,0,0,0,0};
            }
            f32x4 wk4 = *(const f32x4*)(wbt + k*80 + g*16);  // weights for D rows 4g..4g+3
#pragma unroll
            for (int j = 0; j < 4; ++j) {
                f32x4 d = mfma16(af, wH[j], zero4);
#pragma unroll
                for (int r = 0; r < 4; ++r)
                    hba[j][r] += wk4[r] * fmaxf(d[r] + of2r[j], 0.0f);
            }
        }
        // hb write: D rows q = 4g+r, cols o = 64wv+16j+l15; bf16 hi | lo halves
#pragma unroll
        for (int j = 0; j < 4; ++j)
#pragma unroll
            for (int r = 0; r < 4; ++r) {
                int q = g*4 + r;
                int o = wv*64 + j*16 + l15;
                float x = hba[j][r];
                u16 h = f2bf(x); u16 l = f2bf(x - bf(h));
                *(u16*)(hbm_ + q*1040 + (size_t)o*2)       = h;
                *(u16*)(hbm_ + q*1040 + 512 + (size_t)o*2) = l;
            }
    }
    __syncthreads();

    // ---- layer2: [16 x 512(hi|lo)] x [512 x 64]; hi/lo fused per ks (one bw live);
    //      unroll 2 caps live fragments at ~3 chunks. ----
    {
        f32x4 acA = zero4, acB = zero4;
#pragma unroll 2
        for (int ks = 0; ks < 8; ++ks) {
            bh8 bw = ldb(cb + (size_t)o_lane*512 + ks*64 + g*16);
            bh8 aH = ldb(hbm_ + l15*1040 + ks*64 + g*16);
            bh8 aL = ldb(hbm_ + l15*1040 + 512 + ks*64 + g*16);
            acA = mfma16(aH, bw, acA);
            acB = mfma16(aL, bw, acB);
        }
        f32x4 wsb4 = *(const f32x4*)(wsbp + g*16);
#pragma unroll
        for (int r = 0; r < 4; ++r) {
            int q = g*4 + r;
            float pf = acA[r] + acB[r] + b2bo * wsb4[r];
            u16 h = f2bf(pf); u16 l = f2bf(pf - bf(h));
            *(u16*)(dfm + q*784 + (size_t)(128 + o_lane)*2) = h;
            *(u16*)(dfm + q*784 + (size_t)(320 + o_lane)*2) = l;
        }
    }
    __syncthreads();

    // ---- layer 1d: [16 x 384(hi|lo)] x [384 x 64], fused hi/lo, BN+ReLU -> h1 (overlays dpb) ----
    {
        f32x4 acA = zero4, acB = zero4;
#pragma unroll 2
        for (int ks = 0; ks < 6; ++ks) {
            bh8 bw = ldb(cb + 32768 + (size_t)o_lane*384 + ks*64 + g*16);
            bh8 aH = ldb(dfm + l15*784 + ks*64 + g*16);
            bh8 aL = ldb(dfm + l15*784 + 384 + ks*64 + g*16);
            acA = mfma16(aH, bw, acA);
            acB = mfma16(aL, bw, acB);
        }
#pragma unroll
        for (int r = 0; r < 4; ++r) {
            int q = g*4 + r;
            float z = (acA[r] + acB[r]) * s1o + o1o;
            z = fmaxf(z, 0.0f);
            u16 h = f2bf(z); u16 l = f2bf(z - bf(h));
            *(u16*)(h1m + q*272 + (size_t)o_lane*2)       = h;
            *(u16*)(h1m + q*272 + 128 + (size_t)o_lane*2) = l;
        }
    }
    __syncthreads();

    // ---- layer 2d: [16 x 128(hi|lo)] x [128 x 64], bias, store ----
    {
        bh8 bw0 = ldb(cb + 57344 + (size_t)o_lane*128 + g*16);
        bh8 bw1 = ldb(cb + 57344 + (size_t)o_lane*128 + 64 + g*16);
        f32x4 ac = zero4;
        { bh8 a = ldb(h1m + l15*272 +   0 + g*16); ac = mfma16(a, bw0, ac); }
        { bh8 a = ldb(h1m + l15*272 +  64 + g*16); ac = mfma16(a, bw1, ac); }
        { bh8 a = ldb(h1m + l15*272 + 128 + g*16); ac = mfma16(a, bw0, ac); }
        { bh8 a = ldb(h1m + l15*272 + 192 + g*16); ac = mfma16(a, bw1, ac); }
#pragma unroll
        for (int r = 0; r < 4; ++r) {
            int q = g*4 + r;
            float ov = ac[r] + b1fo;
            size_t ob = ((size_t)(qbb + q) << 6) + o_lane;
            if (f32) ((float*)outp)[ob] = ov;
            else     ((u16*)outp)[ob]   = f2bf(ov);
        }
    }
}

extern "C" void kernel_launch(void* const* d_in, const int* in_sizes, int n_in,
                              void* d_out, int out_size, void* d_ws, size_t ws_size,
                              hipStream_t stream) {
    const void* pcl   = d_in[0];
    const void* noise = d_in[1];
    const void* feat  = d_in[2];
    const void* w2a   = d_in[3];
    const void* b2a   = d_in[4];
    const void* g2a   = d_in[5];
    const void* bt2a  = d_in[6];
    const void* w2b   = d_in[7];
    const void* b2b   = d_in[8];
    const void* w1a   = d_in[9];
    const void* b1a   = d_in[10];
    const void* g1a   = d_in[11];
    const void* bt1a  = d_in[12];
    const void* w1b   = d_in[13];
    const void* b1b   = d_in[14];

    char* ws = (char*)d_ws;
    float4* pcl4 = (float4*)ws;                    // 128 KB: [B,M] x (x,y,z,sumsq)
    u16* cidx = (u16*)(ws + 131072);               // 32 KB: [B,N]
    u16* knn  = (u16*)(ws + 163840);               // 256 KB: [B,M,16]
    u32* canonb = (u32*)(ws + 425984);             // 64 KB: bf16-pair w2b|w1a|w1b
    // total workspace: 491,520 bytes

    k_pre  <<<96,   256, 0, stream>>>(noise, w2b, w1a, w1b, canonb, pcl, pcl4);
    k_close<<<1024, 256, 0, stream>>>(pcl4, noise, cidx);
    k_knnh <<<8192, 256, 0, stream>>>(pcl4, knn);
    k_tail <<<1024, 256, 0, stream>>>(pcl4, noise, feat, cidx, knn,
                                      w2a, b2a, g2a, bt2a, canonb, b2b,
                                      b1a, g1a, bt1a, b1b, d_out);
}